// Round 1
// baseline (1834.324 us; speedup 1.0000x reference)
//
#include <hip/hip_runtime.h>
#include <cmath>
#include <cstdint>
#include <cstddef>
#include <climits>

#define N_SRC 65536
#define N_TGT 1024
#define DIM   256
#define TAU_INV (1.0f/0.07f)
#define LOSS_EPS 1e-6f
#define TOPSEL 512
#define NBI (N_SRC/128)     // 512 row-blocks of the GEMM grid

typedef __bf16 bf16x8 __attribute__((ext_vector_type(8)));
typedef float  f32x4  __attribute__((ext_vector_type(4)));

// ---------------- bf16 split helpers ------------------------------------------------
__device__ __forceinline__ unsigned short f2bf(float x) {
  unsigned u = __float_as_uint(x);
  unsigned r = (u + 0x7fffu + ((u >> 16) & 1u)) >> 16;
  return (unsigned short)r;
}
__device__ __forceinline__ float bf2f(unsigned short h) {
  return __uint_as_float(((unsigned)h) << 16);
}

// ---------------- top-5 insertion helpers -------------------------------------------
__device__ __forceinline__ void insert5_vi(float v[5], int id[5], float nv, int ni) {
  bool beats_last = (nv > v[4]) || (nv == v[4] && ni < id[4]);
  if (!beats_last) return;
  #pragma unroll
  for (int p = 4; p > 0; --p) {
    bool up = (nv > v[p-1]) || (nv == v[p-1] && ni < id[p-1]);
    if (up) { v[p] = v[p-1]; id[p] = id[p-1]; }
    else    { v[p] = nv; id[p] = ni; return; }
  }
  v[0] = nv; id[0] = ni;
}
__device__ __forceinline__ void insert5_v(float v[5], float nv) {
  if (!(nv > v[4])) return;
  #pragma unroll
  for (int p = 4; p > 0; --p) {
    if (nv > v[p-1]) v[p] = v[p-1];
    else { v[p] = nv; return; }
  }
  v[0] = nv;
}
// butterfly merge across the 64-lane wave: all lanes end with the wave's top-5
__device__ __forceinline__ void wave_merge5_vi(float v[5], int id[5]) {
  #pragma unroll
  for (int off = 1; off < 64; off <<= 1) {
    float pv[5]; int pi[5];
    #pragma unroll
    for (int u = 0; u < 5; ++u) {
      pv[u] = __shfl_xor(v[u], off, 64);
      pi[u] = __shfl_xor(id[u], off, 64);
    }
    #pragma unroll
    for (int u = 0; u < 5; ++u) insert5_vi(v, id, pv[u], pi[u]);
  }
}
__device__ __forceinline__ void wave_merge5_v(float v[5]) {
  #pragma unroll
  for (int off = 1; off < 64; off <<= 1) {
    float pv[5];
    #pragma unroll
    for (int u = 0; u < 5; ++u) pv[u] = __shfl_xor(v[u], off, 64);
    #pragma unroll
    for (int u = 0; u < 5; ++u) insert5_v(v, pv[u]);
  }
}

// ---------------- K1: row-normalize + split fp32 -> (hi, lo) bf16 -------------------
// one wave per row (64 lanes x float4 = 256 elems)
__global__ __launch_bounds__(256) void k_norm_split(const float* __restrict__ X,
                                                    unsigned short* __restrict__ hi,
                                                    unsigned short* __restrict__ lo) {
  int wave = threadIdx.x >> 6, lane = threadIdx.x & 63;
  int row  = blockIdx.x * 4 + wave;
  float4 v = reinterpret_cast<const float4*>(X + (size_t)row * DIM)[lane];
  float ss = v.x*v.x + v.y*v.y + v.z*v.z + v.w*v.w;
  #pragma unroll
  for (int o = 32; o > 0; o >>= 1) ss += __shfl_xor(ss, o, 64);
  float r = 1.0f / sqrtf(ss);
  v.x *= r; v.y *= r; v.z *= r; v.w *= r;
  ushort4 h, l;
  h.x = f2bf(v.x); l.x = f2bf(v.x - bf2f(h.x));
  h.y = f2bf(v.y); l.y = f2bf(v.y - bf2f(h.y));
  h.z = f2bf(v.z); l.z = f2bf(v.z - bf2f(h.z));
  h.w = f2bf(v.w); l.w = f2bf(v.w - bf2f(h.w));
  reinterpret_cast<ushort4*>(hi + (size_t)row * DIM)[lane] = h;
  reinterpret_cast<ushort4*>(lo + (size_t)row * DIM)[lane] = l;
}

// ---------------- K2: fused split-bf16 MFMA GEMM + reduction epilogue ---------------
// 128x128 tile, BK=32 bf16, 4 waves in 2x2, each wave 4x4 frags of 16x16x32.
// 3 MFMAs per frag pair: hi*hi + hi*lo + lo*hi (lo*lo dropped, ~2^-18 rel).
// PHASE 1 epilogue: per-column top-5 (val,idx) over this block's 128 rows.
// PHASE 2 epilogue: per-column {sum exp, sum exp matched, top5 matched, top5 unmatched}.
__device__ __forceinline__ void gl_lds(const unsigned short* g, unsigned short* d) {
  __builtin_amdgcn_global_load_lds(
      (const __attribute__((address_space(1))) unsigned int*)g,
      (__attribute__((address_space(3))) unsigned int*)d, 16, 0, 0);
}

template<int PHASE>
__global__ __launch_bounds__(256) void k_gemm_fused(
    const unsigned short* __restrict__ Ahi, const unsigned short* __restrict__ Alo,
    const unsigned short* __restrict__ Bhi, const unsigned short* __restrict__ Blo,
    const int* __restrict__ labels, const int* __restrict__ assigned,
    float* __restrict__ p1v, int* __restrict__ p1i, float* __restrict__ p2p)
{
  __shared__ unsigned short smem[4 * 128 * 32];   // K-loop staging; reused by epilogue
  __shared__ int lab_s[128];
  __shared__ int asg_s[128];
  unsigned short* As_hi = smem;
  unsigned short* As_lo = smem + 128 * 32;
  unsigned short* Bs_hi = smem + 2 * 128 * 32;
  unsigned short* Bs_lo = smem + 3 * 128 * 32;

  const int tid  = threadIdx.x;
  const int lane = tid & 63;
  const int w    = tid >> 6;       // wave 0..3
  const int wm   = w & 1;          // src-dim half
  const int wn   = w >> 1;         // tgt-dim half
  const int bi   = blockIdx.x;
  const int i0   = bi * 128;
  const int j0   = blockIdx.y * 128;

  if constexpr (PHASE == 2) {
    if (tid < 128) {
      lab_s[tid] = labels[i0 + tid];
      asg_s[tid] = assigned[j0 + tid];
    }
  }

  f32x4 acc[4][4];
  #pragma unroll
  for (int a = 0; a < 4; ++a)
    #pragma unroll
    for (int b = 0; b < 4; ++b) acc[a][b] = f32x4{0.f, 0.f, 0.f, 0.f};

  // staging addresses: wave w covers rows [w*32, w*32+32), 16 rows per instruction
  const int srow = (w << 5) + (lane >> 2);
  const int scol = (lane & 3) << 3;             // element offset (8 bf16 = 16 B)
  const unsigned short* gAh = Ahi + (size_t)(i0 + srow) * DIM + scol;
  const unsigned short* gAl = Alo + (size_t)(i0 + srow) * DIM + scol;
  const unsigned short* gBh = Bhi + (size_t)(j0 + srow) * DIM + scol;
  const unsigned short* gBl = Blo + (size_t)(j0 + srow) * DIM + scol;
  unsigned short* dA0  = &As_hi[(w << 5) * 32];
  unsigned short* dA1  = &As_hi[((w << 5) + 16) * 32];
  unsigned short* dB0  = &Bs_hi[(w << 5) * 32];
  unsigned short* dB1  = &Bs_hi[((w << 5) + 16) * 32];
  unsigned short* dA0l = &As_lo[(w << 5) * 32];
  unsigned short* dA1l = &As_lo[((w << 5) + 16) * 32];
  unsigned short* dB0l = &Bs_lo[(w << 5) * 32];
  unsigned short* dB1l = &Bs_lo[((w << 5) + 16) * 32];

  const int fr = lane & 15;            // fragment row (m or n)
  const int fk = (lane >> 4) << 3;     // fragment k offset

  for (int k0 = 0; k0 < DIM; k0 += 32) {
    __syncthreads();   // previous compute done before LDS overwrite
    gl_lds(gAh + k0,           dA0);
    gl_lds(gAh + k0 + 16*DIM,  dA1);
    gl_lds(gAl + k0,           dA0l);
    gl_lds(gAl + k0 + 16*DIM,  dA1l);
    gl_lds(gBh + k0,           dB0);
    gl_lds(gBh + k0 + 16*DIM,  dB1);
    gl_lds(gBl + k0,           dB0l);
    gl_lds(gBl + k0 + 16*DIM,  dB1l);
    __syncthreads();   // compiler drains vmcnt before s_barrier

    bf16x8 ah[4], al[4], bh[4], bl[4];
    #pragma unroll
    for (int rf = 0; rf < 4; ++rf) {
      int r = ((wm << 6) + (rf << 4) + fr) * 32 + fk;
      ah[rf] = *(const bf16x8*)&As_hi[r];
      al[rf] = *(const bf16x8*)&As_lo[r];
    }
    #pragma unroll
    for (int cf = 0; cf < 4; ++cf) {
      int r = ((wn << 6) + (cf << 4) + fr) * 32 + fk;
      bh[cf] = *(const bf16x8*)&Bs_hi[r];
      bl[cf] = *(const bf16x8*)&Bs_lo[r];
    }
    #pragma unroll
    for (int rf = 0; rf < 4; ++rf)
      #pragma unroll
      for (int cf = 0; cf < 4; ++cf) {
        acc[rf][cf] = __builtin_amdgcn_mfma_f32_16x16x32_bf16(ah[rf], bh[cf], acc[rf][cf], 0, 0, 0);
        acc[rf][cf] = __builtin_amdgcn_mfma_f32_16x16x32_bf16(ah[rf], bl[cf], acc[rf][cf], 0, 0, 0);
        acc[rf][cf] = __builtin_amdgcn_mfma_f32_16x16x32_bf16(al[rf], bh[cf], acc[rf][cf], 0, 0, 0);
      }
  }

  // acc mapping: col n = wn*64 + cf*16 + (lane&15); row m = wm*64 + rf*16 + (lane>>4)*4 + reg
  __syncthreads();   // all waves done with LDS -> reuse as epilogue scratch

  if constexpr (PHASE == 1) {
    float* ep_v = reinterpret_cast<float*>(smem);          // [2][128][5]
    int*   ep_i = reinterpret_cast<int*>(smem) + 2*128*5;  // [2][128][5]
    #pragma unroll
    for (int cf = 0; cf < 4; ++cf) {
      float tv[5]; int ti[5];
      #pragma unroll
      for (int u = 0; u < 5; ++u) { tv[u] = -INFINITY; ti[u] = INT_MAX; }
      #pragma unroll
      for (int rf = 0; rf < 4; ++rf) {
        const int mb = i0 + (wm << 6) + (rf << 4) + ((lane >> 4) << 2);
        #pragma unroll
        for (int r = 0; r < 4; ++r) insert5_vi(tv, ti, acc[rf][cf][r], mb + r);
      }
      // merge the 4 row-subgroups sharing this column (lanes differing in bits 4-5)
      #pragma unroll
      for (int off = 16; off < 64; off <<= 1) {
        float pv[5]; int pi[5];
        #pragma unroll
        for (int u = 0; u < 5; ++u) { pv[u] = __shfl_xor(tv[u], off, 64); pi[u] = __shfl_xor(ti[u], off, 64); }
        #pragma unroll
        for (int u = 0; u < 5; ++u) insert5_vi(tv, ti, pv[u], pi[u]);
      }
      if (lane < 16) {
        const int col = (wn << 6) + (cf << 4) + lane;
        #pragma unroll
        for (int u = 0; u < 5; ++u) { ep_v[(wm*128 + col)*5 + u] = tv[u]; ep_i[(wm*128 + col)*5 + u] = ti[u]; }
      }
    }
    __syncthreads();
    if (tid < 128) {
      float v[5]; int id[5];
      #pragma unroll
      for (int u = 0; u < 5; ++u) { v[u] = -INFINITY; id[u] = INT_MAX; }
      #pragma unroll
      for (int h = 0; h < 2; ++h)
        #pragma unroll
        for (int u = 0; u < 5; ++u)
          insert5_vi(v, id, ep_v[(h*128 + tid)*5 + u], ep_i[(h*128 + tid)*5 + u]);
      const size_t o = ((size_t)(j0 + tid) * NBI + bi) * 5;
      #pragma unroll
      for (int u = 0; u < 5; ++u) { p1v[o+u] = v[u]; p1i[o+u] = id[u]; }
    }
  } else {
    float* ep = reinterpret_cast<float*>(smem);            // [2][128][12]
    #pragma unroll
    for (int cf = 0; cf < 4; ++cf) {
      const int col = (wn << 6) + (cf << 4) + (lane & 15);
      const int asg = asg_s[col];
      float se = 0.f, sem = 0.f;
      float mt[5], ut[5];
      #pragma unroll
      for (int u = 0; u < 5; ++u) { mt[u] = -INFINITY; ut[u] = -INFINITY; }
      #pragma unroll
      for (int rf = 0; rf < 4; ++rf) {
        const int mb = (wm << 6) + (rf << 4) + ((lane >> 4) << 2);
        #pragma unroll
        for (int r = 0; r < 4; ++r) {
          const float val = acc[rf][cf][r];
          const float e = __expf(val * TAU_INV);
          se += e;
          if (lab_s[mb + r] == asg) { sem += e; insert5_v(mt, val); }
          else insert5_v(ut, val);
        }
      }
      #pragma unroll
      for (int off = 16; off < 64; off <<= 1) {
        se  += __shfl_xor(se,  off, 64);
        sem += __shfl_xor(sem, off, 64);
        float pm[5], pu[5];
        #pragma unroll
        for (int u = 0; u < 5; ++u) { pm[u] = __shfl_xor(mt[u], off, 64); pu[u] = __shfl_xor(ut[u], off, 64); }
        #pragma unroll
        for (int u = 0; u < 5; ++u) { insert5_v(mt, pm[u]); insert5_v(ut, pu[u]); }
      }
      if (lane < 16) {
        float* d = ep + (wm*128 + col) * 12;
        d[0] = se; d[1] = sem;
        #pragma unroll
        for (int u = 0; u < 5; ++u) { d[2+u] = mt[u]; d[7+u] = ut[u]; }
      }
    }
    __syncthreads();
    if (tid < 128) {
      const float* a = ep + (size_t)tid * 12;
      const float* b = ep + (size_t)(128 + tid) * 12;
      float se = a[0] + b[0], sem = a[1] + b[1];
      float mt[5], ut[5];
      #pragma unroll
      for (int u = 0; u < 5; ++u) { mt[u] = -INFINITY; ut[u] = -INFINITY; }
      #pragma unroll
      for (int u = 0; u < 5; ++u) {
        insert5_v(mt, a[2+u]); insert5_v(mt, b[2+u]);
        insert5_v(ut, a[7+u]); insert5_v(ut, b[7+u]);
      }
      const size_t o = ((size_t)(j0 + tid) * NBI + bi) * 12;
      p2p[o+0] = se; p2p[o+1] = sem;
      #pragma unroll
      for (int u = 0; u < 5; ++u) { p2p[o+2+u] = mt[u]; p2p[o+7+u] = ut[u]; }
    }
  }
}

// ---------------- K3: merge row-block top-5s -> assigned label per column -----------
__global__ __launch_bounds__(256) void k_assign2(const float* __restrict__ p1v,
                                                 const int* __restrict__ p1i,
                                                 const int* __restrict__ labels,
                                                 int* __restrict__ assigned) {
  const int w = threadIdx.x >> 6, lane = threadIdx.x & 63;
  const int j = blockIdx.x * 4 + w;
  const float* pv = p1v + (size_t)j * NBI * 5;
  const int*   pi = p1i + (size_t)j * NBI * 5;
  float v[5]; int id[5];
  #pragma unroll
  for (int u = 0; u < 5; ++u) { v[u] = -INFINITY; id[u] = INT_MAX; }
  for (int b = lane; b < NBI; b += 64) {
    #pragma unroll
    for (int u = 0; u < 5; ++u) insert5_vi(v, id, pv[b*5 + u], pi[b*5 + u]);
  }
  wave_merge5_vi(v, id);
  if (lane == 0) {
    int lab[5];
    #pragma unroll
    for (int a = 0; a < 5; ++a) lab[a] = labels[id[a]];
    int bestSc = INT_MIN, bestA = 0;
    #pragma unroll
    for (int a = 0; a < 5; ++a) {
      int c = 0;
      #pragma unroll
      for (int b = 0; b < 5; ++b) c += (lab[b] == lab[a]) ? 1 : 0;
      int sc = c * 1000000 - lab[a];
      if (sc > bestSc) { bestSc = sc; bestA = a; }
    }
    assigned[j] = lab[bestA];
  }
}

// ---------------- K4: merge row-block stats -> scores, contrast ---------------------
__global__ __launch_bounds__(256) void k_score2(const float* __restrict__ p2p,
                                                float* __restrict__ scores,
                                                float* __restrict__ contrast) {
  const int w = threadIdx.x >> 6, lane = threadIdx.x & 63;
  const int j = blockIdx.x * 4 + w;
  const float* p = p2p + (size_t)j * NBI * 12;
  float se = 0.f, sem = 0.f;
  float mt[5], ut[5];
  #pragma unroll
  for (int u = 0; u < 5; ++u) { mt[u] = -INFINITY; ut[u] = -INFINITY; }
  for (int b = lane; b < NBI; b += 64) {
    se  += p[b*12 + 0];
    sem += p[b*12 + 1];
    #pragma unroll
    for (int u = 0; u < 5; ++u) { insert5_v(mt, p[b*12 + 2 + u]); insert5_v(ut, p[b*12 + 7 + u]); }
  }
  #pragma unroll
  for (int o = 32; o > 0; o >>= 1) { se += __shfl_xor(se, o, 64); sem += __shfl_xor(sem, o, 64); }
  wave_merge5_v(mt);
  wave_merge5_v(ut);
  if (lane == 0) {
    float nln = 0.f, nun = 0.f;
    #pragma unroll
    for (int u = 0; u < 5; ++u) {
      if (mt[u] > -1e30f) nln += mt[u];
      if (ut[u] > -1e30f) nun += ut[u];
    }
    scores[j]   = nln / nun;
    contrast[j] = sem / se;
  }
}

// ---------------- K5: top-512 selection + loss --------------------------------------
__global__ __launch_bounds__(1024) void k_finalize(const float* __restrict__ scores,
                                                   const float* __restrict__ contrast,
                                                   float* __restrict__ out) {
  __shared__ float sc[N_TGT];
  __shared__ float red[N_TGT];
  const int j = threadIdx.x;
  sc[j] = scores[j];
  __syncthreads();
  float my = sc[j];
  int rank = 0;
  for (int m = 0; m < N_TGT; ++m) {
    float s = sc[m];
    rank += ((s > my) || (s == my && m < j)) ? 1 : 0;
  }
  red[j] = (rank < TOPSEL) ? logf(contrast[j] + LOSS_EPS) : 0.0f;
  __syncthreads();
  for (int s = 512; s > 0; s >>= 1) { if (j < s) red[j] += red[j+s]; __syncthreads(); }
  if (j == 0) out[0] = -red[0] / (float)TOPSEL;
}

// ---------------- launcher ----------------------------------------------------------
extern "C" void kernel_launch(void* const* d_in, const int* in_sizes, int n_in,
                              void* d_out, int out_size, void* d_ws, size_t ws_size,
                              hipStream_t stream) {
  const float* S      = (const float*)d_in[0];
  const int*   labels = (const int*)d_in[1];
  const float* T      = (const float*)d_in[2];
  float* out = (float*)d_out;

  float* ws = (float*)d_ws;
  float* scores    = ws;                                    // 1024
  float* contrastA = scores + N_TGT;                        // 1024
  int*   assigned  = (int*)(contrastA + N_TGT);             // 1024
  float* p1v       = (float*)(assigned + N_TGT);            // N_TGT*NBI*5  = 2.62M f
  int*   p1i       = (int*)(p1v + (size_t)N_TGT*NBI*5);     // 2.62M i
  float* p2p       = (float*)(p1i + (size_t)N_TGT*NBI*5);   // N_TGT*NBI*12 = 3.15M f
  unsigned short* Shi = (unsigned short*)(p2p + (size_t)N_TGT*NBI*12); // 65536*256
  unsigned short* Slo = Shi + (size_t)N_SRC*DIM;
  unsigned short* Thi = Slo + (size_t)N_SRC*DIM;            // 1024*256
  unsigned short* Tlo = Thi + (size_t)N_TGT*DIM;

  k_norm_split<<<N_TGT/4, 256, 0, stream>>>(T, Thi, Tlo);
  k_norm_split<<<N_SRC/4, 256, 0, stream>>>(S, Shi, Slo);

  dim3 gg(NBI, N_TGT/128);
  k_gemm_fused<1><<<gg, 256, 0, stream>>>(Shi, Slo, Thi, Tlo, labels, assigned, p1v, p1i, p2p);
  k_assign2<<<N_TGT/4, 256, 0, stream>>>(p1v, p1i, labels, assigned);
  k_gemm_fused<2><<<gg, 256, 0, stream>>>(Shi, Slo, Thi, Tlo, labels, assigned, p1v, p1i, p2p);
  k_score2<<<N_TGT/4, 256, 0, stream>>>(p2p, scores, contrastA);
  k_finalize<<<1, 1024, 0, stream>>>(scores, contrastA, out);
}

// Round 2
// 1744.555 us; speedup vs baseline: 1.0515x; 1.0515x over previous
//
#include <hip/hip_runtime.h>
#include <cmath>
#include <cstdint>
#include <cstddef>
#include <climits>

#define N_SRC 65536
#define N_TGT 1024
#define DIM   256
#define TAU_INV (1.0f/0.07f)
#define LOSS_EPS 1e-6f
#define TOPSEL 512
#define NBI (N_SRC/128)     // 512 row-blocks of the GEMM grid
#define NBJ (N_TGT/128)     // 8 col-blocks

typedef __bf16 bf16x8 __attribute__((ext_vector_type(8)));
typedef float  f32x4  __attribute__((ext_vector_type(4)));

// ---------------- bf16 split helpers ------------------------------------------------
__device__ __forceinline__ unsigned short f2bf(float x) {
  unsigned u = __float_as_uint(x);
  unsigned r = (u + 0x7fffu + ((u >> 16) & 1u)) >> 16;
  return (unsigned short)r;
}
__device__ __forceinline__ float bf2f(unsigned short h) {
  return __uint_as_float(((unsigned)h) << 16);
}

// ---------------- top-5 insertion helpers -------------------------------------------
__device__ __forceinline__ void insert5_vi(float v[5], int id[5], float nv, int ni) {
  bool beats_last = (nv > v[4]) || (nv == v[4] && ni < id[4]);
  if (!beats_last) return;
  #pragma unroll
  for (int p = 4; p > 0; --p) {
    bool up = (nv > v[p-1]) || (nv == v[p-1] && ni < id[p-1]);
    if (up) { v[p] = v[p-1]; id[p] = id[p-1]; }
    else    { v[p] = nv; id[p] = ni; return; }
  }
  v[0] = nv; id[0] = ni;
}
__device__ __forceinline__ void insert5_v(float v[5], float nv) {
  if (!(nv > v[4])) return;
  #pragma unroll
  for (int p = 4; p > 0; --p) {
    if (nv > v[p-1]) v[p] = v[p-1];
    else { v[p] = nv; return; }
  }
  v[0] = nv;
}
// butterfly merge across the 64-lane wave: all lanes end with the wave's top-5
__device__ __forceinline__ void wave_merge5_vi(float v[5], int id[5]) {
  #pragma unroll
  for (int off = 1; off < 64; off <<= 1) {
    float pv[5]; int pi[5];
    #pragma unroll
    for (int u = 0; u < 5; ++u) {
      pv[u] = __shfl_xor(v[u], off, 64);
      pi[u] = __shfl_xor(id[u], off, 64);
    }
    #pragma unroll
    for (int u = 0; u < 5; ++u) insert5_vi(v, id, pv[u], pi[u]);
  }
}
__device__ __forceinline__ void wave_merge5_v(float v[5]) {
  #pragma unroll
  for (int off = 1; off < 64; off <<= 1) {
    float pv[5];
    #pragma unroll
    for (int u = 0; u < 5; ++u) pv[u] = __shfl_xor(v[u], off, 64);
    #pragma unroll
    for (int u = 0; u < 5; ++u) insert5_v(v, pv[u]);
  }
}

// ---------------- K1: row-normalize + split fp32 -> (hi, lo) bf16 -------------------
// one wave per row (64 lanes x float4 = 256 elems)
__global__ __launch_bounds__(256) void k_norm_split(const float* __restrict__ X,
                                                    unsigned short* __restrict__ hi,
                                                    unsigned short* __restrict__ lo) {
  int wave = threadIdx.x >> 6, lane = threadIdx.x & 63;
  int row  = blockIdx.x * 4 + wave;
  float4 v = reinterpret_cast<const float4*>(X + (size_t)row * DIM)[lane];
  float ss = v.x*v.x + v.y*v.y + v.z*v.z + v.w*v.w;
  #pragma unroll
  for (int o = 32; o > 0; o >>= 1) ss += __shfl_xor(ss, o, 64);
  float r = 1.0f / sqrtf(ss);
  v.x *= r; v.y *= r; v.z *= r; v.w *= r;
  ushort4 h, l;
  h.x = f2bf(v.x); l.x = f2bf(v.x - bf2f(h.x));
  h.y = f2bf(v.y); l.y = f2bf(v.y - bf2f(h.y));
  h.z = f2bf(v.z); l.z = f2bf(v.z - bf2f(h.z));
  h.w = f2bf(v.w); l.w = f2bf(v.w - bf2f(h.w));
  reinterpret_cast<ushort4*>(hi + (size_t)row * DIM)[lane] = h;
  reinterpret_cast<ushort4*>(lo + (size_t)row * DIM)[lane] = l;
}

// ---------------- K2: fused split-bf16 MFMA GEMM + reduction epilogue ---------------
// 128x128 tile, BK=32 bf16, 4 waves in 2x2, each wave 4x4 frags of 16x16x32.
// 3 MFMAs per frag pair: hi*hi + hi*lo + lo*hi (lo*lo dropped, ~2^-18 rel).
// Double-buffered staging (2-phase pipeline): issue next tile's global_load_lds
// BEFORE computing current tile; single vmcnt-drain+barrier per tile (__syncthreads).
// XCD-aware remap: blocks d%8==c form XCD c's stream; each bi-panel's 8 bj-tiles are
// consecutive on one XCD -> A fetched once into that XCD's L2, 7 reuse hits.
// PHASE 1 epilogue: per-column top-5 (val,idx) over this block's 128 rows.
// PHASE 2 epilogue: per-column {sum exp, sum exp matched, top5 matched, top5 unmatched}.
__device__ __forceinline__ void gl_lds(const unsigned short* g, unsigned short* d) {
  __builtin_amdgcn_global_load_lds(
      (const __attribute__((address_space(1))) unsigned int*)g,
      (__attribute__((address_space(3))) unsigned int*)d, 16, 0, 0);
}

template<int PHASE>
__global__ __launch_bounds__(256) void k_gemm_fused(
    const unsigned short* __restrict__ Ahi, const unsigned short* __restrict__ Alo,
    const unsigned short* __restrict__ Bhi, const unsigned short* __restrict__ Blo,
    const int* __restrict__ labels, const int* __restrict__ assigned,
    float* __restrict__ p1v, int* __restrict__ p1i, float* __restrict__ p2p)
{
  __shared__ unsigned short bufA[4 * 128 * 32];   // tiles 0,2,4,6 ; epilogue scratch
  __shared__ unsigned short bufB[4 * 128 * 32];   // tiles 1,3,5,7
  __shared__ int lab_s[128];
  __shared__ int asg_s[128];

  const int tid  = threadIdx.x;
  const int lane = tid & 63;
  const int w    = tid >> 6;       // wave 0..3
  const int wm   = w & 1;          // src-dim half
  const int wn   = w >> 1;         // tgt-dim half

  // bijective XCD-locality remap: d = c + 8*k, bj = k%8, bi = (k/8)*8 + c
  const int d  = blockIdx.x;
  const int c  = d & 7;
  const int kk = d >> 3;
  const int bj = kk & 7;
  const int bi = ((kk >> 3) << 3) | c;
  const int i0 = bi * 128;
  const int j0 = bj * 128;

  if constexpr (PHASE == 2) {
    if (tid < 128) {
      lab_s[tid] = labels[i0 + tid];
      asg_s[tid] = assigned[j0 + tid];
    }
  }

  f32x4 acc[4][4];
  #pragma unroll
  for (int a = 0; a < 4; ++a)
    #pragma unroll
    for (int b = 0; b < 4; ++b) acc[a][b] = f32x4{0.f, 0.f, 0.f, 0.f};

  // staging addresses: wave w covers rows [w*32, w*32+32), 16 rows per instruction
  const int srow = (w << 5) + (lane >> 2);
  const int scol = (lane & 3) << 3;             // element offset (8 bf16 = 16 B)
  const unsigned short* gAh = Ahi + (size_t)(i0 + srow) * DIM + scol;
  const unsigned short* gAl = Alo + (size_t)(i0 + srow) * DIM + scol;
  const unsigned short* gBh = Bhi + (size_t)(j0 + srow) * DIM + scol;
  const unsigned short* gBl = Blo + (size_t)(j0 + srow) * DIM + scol;

  auto stage = [&](int k0, unsigned short* s) {
    unsigned short* sAh = s;
    unsigned short* sAl = s + 128*32;
    unsigned short* sBh = s + 2*128*32;
    unsigned short* sBl = s + 3*128*32;
    gl_lds(gAh + k0,          sAh + (w << 5) * 32);
    gl_lds(gAh + k0 + 16*DIM, sAh + ((w << 5) + 16) * 32);
    gl_lds(gAl + k0,          sAl + (w << 5) * 32);
    gl_lds(gAl + k0 + 16*DIM, sAl + ((w << 5) + 16) * 32);
    gl_lds(gBh + k0,          sBh + (w << 5) * 32);
    gl_lds(gBh + k0 + 16*DIM, sBh + ((w << 5) + 16) * 32);
    gl_lds(gBl + k0,          sBl + (w << 5) * 32);
    gl_lds(gBl + k0 + 16*DIM, sBl + ((w << 5) + 16) * 32);
  };

  const int fr = lane & 15;            // fragment row (m or n)
  const int fk = (lane >> 4) << 3;     // fragment k offset

  stage(0, bufA);
  __syncthreads();                      // buf ready (vmcnt drain) + lab/asg visible

  #pragma unroll
  for (int t = 0; t < 8; ++t) {
    const unsigned short* cur = (t & 1) ? bufB : bufA;
    unsigned short*       nxt = (t & 1) ? bufA : bufB;
    if (t < 7) stage((t + 1) << 5, nxt);   // issue next tile EARLY; latency hides under MFMA

    const unsigned short* As_hi = cur;
    const unsigned short* As_lo = cur + 128*32;
    const unsigned short* Bs_hi = cur + 2*128*32;
    const unsigned short* Bs_lo = cur + 3*128*32;

    bf16x8 ah[4], al[4], bh[4], bl[4];
    #pragma unroll
    for (int rf = 0; rf < 4; ++rf) {
      int r = ((wm << 6) + (rf << 4) + fr) * 32 + fk;
      ah[rf] = *(const bf16x8*)&As_hi[r];
      al[rf] = *(const bf16x8*)&As_lo[r];
    }
    #pragma unroll
    for (int cf = 0; cf < 4; ++cf) {
      int r = ((wn << 6) + (cf << 4) + fr) * 32 + fk;
      bh[cf] = *(const bf16x8*)&Bs_hi[r];
      bl[cf] = *(const bf16x8*)&Bs_lo[r];
    }
    #pragma unroll
    for (int rf = 0; rf < 4; ++rf)
      #pragma unroll
      for (int cf = 0; cf < 4; ++cf) {
        acc[rf][cf] = __builtin_amdgcn_mfma_f32_16x16x32_bf16(ah[rf], bh[cf], acc[rf][cf], 0, 0, 0);
        acc[rf][cf] = __builtin_amdgcn_mfma_f32_16x16x32_bf16(ah[rf], bl[cf], acc[rf][cf], 0, 0, 0);
        acc[rf][cf] = __builtin_amdgcn_mfma_f32_16x16x32_bf16(al[rf], bh[cf], acc[rf][cf], 0, 0, 0);
      }

    __syncthreads();   // drains vmcnt (next tile staged) + all waves done reading cur
  }

  // acc mapping: col n = wn*64 + cf*16 + (lane&15); row m = wm*64 + rf*16 + (lane>>4)*4 + reg
  if constexpr (PHASE == 1) {
    float* ep_v = reinterpret_cast<float*>(bufA);          // [2][128][5]
    int*   ep_i = reinterpret_cast<int*>(bufA) + 2*128*5;  // [2][128][5]
    #pragma unroll
    for (int cf = 0; cf < 4; ++cf) {
      float tv[5]; int ti[5];
      #pragma unroll
      for (int u = 0; u < 5; ++u) { tv[u] = -INFINITY; ti[u] = INT_MAX; }
      #pragma unroll
      for (int rf = 0; rf < 4; ++rf) {
        const int mb = i0 + (wm << 6) + (rf << 4) + ((lane >> 4) << 2);
        #pragma unroll
        for (int r = 0; r < 4; ++r) insert5_vi(tv, ti, acc[rf][cf][r], mb + r);
      }
      // merge the 4 row-subgroups sharing this column (lanes differing in bits 4-5)
      #pragma unroll
      for (int off = 16; off < 64; off <<= 1) {
        float pv[5]; int pi[5];
        #pragma unroll
        for (int u = 0; u < 5; ++u) { pv[u] = __shfl_xor(tv[u], off, 64); pi[u] = __shfl_xor(ti[u], off, 64); }
        #pragma unroll
        for (int u = 0; u < 5; ++u) insert5_vi(tv, ti, pv[u], pi[u]);
      }
      if (lane < 16) {
        const int col = (wn << 6) + (cf << 4) + lane;
        #pragma unroll
        for (int u = 0; u < 5; ++u) { ep_v[(wm*128 + col)*5 + u] = tv[u]; ep_i[(wm*128 + col)*5 + u] = ti[u]; }
      }
    }
    __syncthreads();
    if (tid < 128) {
      float v[5]; int id[5];
      #pragma unroll
      for (int u = 0; u < 5; ++u) { v[u] = -INFINITY; id[u] = INT_MAX; }
      #pragma unroll
      for (int h = 0; h < 2; ++h)
        #pragma unroll
        for (int u = 0; u < 5; ++u)
          insert5_vi(v, id, ep_v[(h*128 + tid)*5 + u], ep_i[(h*128 + tid)*5 + u]);
      const size_t o = ((size_t)(j0 + tid) * NBI + bi) * 5;
      #pragma unroll
      for (int u = 0; u < 5; ++u) { p1v[o+u] = v[u]; p1i[o+u] = id[u]; }
    }
  } else {
    float* ep = reinterpret_cast<float*>(bufA);            // [2][128][12]
    #pragma unroll
    for (int cf = 0; cf < 4; ++cf) {
      const int col = (wn << 6) + (cf << 4) + (lane & 15);
      const int asg = asg_s[col];
      float se = 0.f, sem = 0.f;
      float mt[5], ut[5];
      #pragma unroll
      for (int u = 0; u < 5; ++u) { mt[u] = -INFINITY; ut[u] = -INFINITY; }
      #pragma unroll
      for (int rf = 0; rf < 4; ++rf) {
        const int mb = (wm << 6) + (rf << 4) + ((lane >> 4) << 2);
        #pragma unroll
        for (int r = 0; r < 4; ++r) {
          const float val = acc[rf][cf][r];
          const float e = __expf(val * TAU_INV);
          se += e;
          if (lab_s[mb + r] == asg) { sem += e; insert5_v(mt, val); }
          else insert5_v(ut, val);
        }
      }
      #pragma unroll
      for (int off = 16; off < 64; off <<= 1) {
        se  += __shfl_xor(se,  off, 64);
        sem += __shfl_xor(sem, off, 64);
        float pm[5], pu[5];
        #pragma unroll
        for (int u = 0; u < 5; ++u) { pm[u] = __shfl_xor(mt[u], off, 64); pu[u] = __shfl_xor(ut[u], off, 64); }
        #pragma unroll
        for (int u = 0; u < 5; ++u) { insert5_v(mt, pm[u]); insert5_v(ut, pu[u]); }
      }
      if (lane < 16) {
        float* dst = ep + (wm*128 + col) * 12;
        dst[0] = se; dst[1] = sem;
        #pragma unroll
        for (int u = 0; u < 5; ++u) { dst[2+u] = mt[u]; dst[7+u] = ut[u]; }
      }
    }
    __syncthreads();
    if (tid < 128) {
      const float* a = ep + (size_t)tid * 12;
      const float* b = ep + (size_t)(128 + tid) * 12;
      float se = a[0] + b[0], sem = a[1] + b[1];
      float mt[5], ut[5];
      #pragma unroll
      for (int u = 0; u < 5; ++u) { mt[u] = -INFINITY; ut[u] = -INFINITY; }
      #pragma unroll
      for (int u = 0; u < 5; ++u) {
        insert5_v(mt, a[2+u]); insert5_v(mt, b[2+u]);
        insert5_v(ut, a[7+u]); insert5_v(ut, b[7+u]);
      }
      const size_t o = ((size_t)(j0 + tid) * NBI + bi) * 12;
      p2p[o+0] = se; p2p[o+1] = sem;
      #pragma unroll
      for (int u = 0; u < 5; ++u) { p2p[o+2+u] = mt[u]; p2p[o+7+u] = ut[u]; }
    }
  }
}

// ---------------- K3: merge row-block top-5s -> assigned label per column -----------
__global__ __launch_bounds__(256) void k_assign2(const float* __restrict__ p1v,
                                                 const int* __restrict__ p1i,
                                                 const int* __restrict__ labels,
                                                 int* __restrict__ assigned) {
  const int w = threadIdx.x >> 6, lane = threadIdx.x & 63;
  const int j = blockIdx.x * 4 + w;
  const float* pv = p1v + (size_t)j * NBI * 5;
  const int*   pi = p1i + (size_t)j * NBI * 5;
  float v[5]; int id[5];
  #pragma unroll
  for (int u = 0; u < 5; ++u) { v[u] = -INFINITY; id[u] = INT_MAX; }
  for (int b = lane; b < NBI; b += 64) {
    #pragma unroll
    for (int u = 0; u < 5; ++u) insert5_vi(v, id, pv[b*5 + u], pi[b*5 + u]);
  }
  wave_merge5_vi(v, id);
  if (lane == 0) {
    int lab[5];
    #pragma unroll
    for (int a = 0; a < 5; ++a) lab[a] = labels[id[a]];
    int bestSc = INT_MIN, bestA = 0;
    #pragma unroll
    for (int a = 0; a < 5; ++a) {
      int cnt = 0;
      #pragma unroll
      for (int b = 0; b < 5; ++b) cnt += (lab[b] == lab[a]) ? 1 : 0;
      int sc = cnt * 1000000 - lab[a];
      if (sc > bestSc) { bestSc = sc; bestA = a; }
    }
    assigned[j] = lab[bestA];
  }
}

// ---------------- K4: merge row-block stats -> scores, contrast ---------------------
__global__ __launch_bounds__(256) void k_score2(const float* __restrict__ p2p,
                                                float* __restrict__ scores,
                                                float* __restrict__ contrast) {
  const int w = threadIdx.x >> 6, lane = threadIdx.x & 63;
  const int j = blockIdx.x * 4 + w;
  const float* p = p2p + (size_t)j * NBI * 12;
  float se = 0.f, sem = 0.f;
  float mt[5], ut[5];
  #pragma unroll
  for (int u = 0; u < 5; ++u) { mt[u] = -INFINITY; ut[u] = -INFINITY; }
  for (int b = lane; b < NBI; b += 64) {
    se  += p[b*12 + 0];
    sem += p[b*12 + 1];
    #pragma unroll
    for (int u = 0; u < 5; ++u) { insert5_v(mt, p[b*12 + 2 + u]); insert5_v(ut, p[b*12 + 7 + u]); }
  }
  #pragma unroll
  for (int o = 32; o > 0; o >>= 1) { se += __shfl_xor(se, o, 64); sem += __shfl_xor(sem, o, 64); }
  wave_merge5_v(mt);
  wave_merge5_v(ut);
  if (lane == 0) {
    float nln = 0.f, nun = 0.f;
    #pragma unroll
    for (int u = 0; u < 5; ++u) {
      if (mt[u] > -1e30f) nln += mt[u];
      if (ut[u] > -1e30f) nun += ut[u];
    }
    scores[j]   = nln / nun;
    contrast[j] = sem / se;
  }
}

// ---------------- K5: top-512 selection + loss --------------------------------------
__global__ __launch_bounds__(1024) void k_finalize(const float* __restrict__ scores,
                                                   const float* __restrict__ contrast,
                                                   float* __restrict__ out) {
  __shared__ float sc[N_TGT];
  __shared__ float red[N_TGT];
  const int j = threadIdx.x;
  sc[j] = scores[j];
  __syncthreads();
  float my = sc[j];
  int rank = 0;
  for (int m = 0; m < N_TGT; ++m) {
    float s = sc[m];
    rank += ((s > my) || (s == my && m < j)) ? 1 : 0;
  }
  red[j] = (rank < TOPSEL) ? logf(contrast[j] + LOSS_EPS) : 0.0f;
  __syncthreads();
  for (int s = 512; s > 0; s >>= 1) { if (j < s) red[j] += red[j+s]; __syncthreads(); }
  if (j == 0) out[0] = -red[0] / (float)TOPSEL;
}

// ---------------- launcher ----------------------------------------------------------
extern "C" void kernel_launch(void* const* d_in, const int* in_sizes, int n_in,
                              void* d_out, int out_size, void* d_ws, size_t ws_size,
                              hipStream_t stream) {
  const float* S      = (const float*)d_in[0];
  const int*   labels = (const int*)d_in[1];
  const float* T      = (const float*)d_in[2];
  float* out = (float*)d_out;

  float* ws = (float*)d_ws;
  float* scores    = ws;                                    // 1024
  float* contrastA = scores + N_TGT;                        // 1024
  int*   assigned  = (int*)(contrastA + N_TGT);             // 1024
  float* p1v       = (float*)(assigned + N_TGT);            // N_TGT*NBI*5  = 2.62M f
  int*   p1i       = (int*)(p1v + (size_t)N_TGT*NBI*5);     // 2.62M i
  float* p2p       = (float*)(p1i + (size_t)N_TGT*NBI*5);   // N_TGT*NBI*12 = 3.15M f
  unsigned short* Shi = (unsigned short*)(p2p + (size_t)N_TGT*NBI*12); // 65536*256
  unsigned short* Slo = Shi + (size_t)N_SRC*DIM;
  unsigned short* Thi = Slo + (size_t)N_SRC*DIM;            // 1024*256
  unsigned short* Tlo = Thi + (size_t)N_TGT*DIM;

  k_norm_split<<<N_TGT/4, 256, 0, stream>>>(T, Thi, Tlo);
  k_norm_split<<<N_SRC/4, 256, 0, stream>>>(S, Shi, Slo);

  k_gemm_fused<1><<<NBI * NBJ, 256, 0, stream>>>(Shi, Slo, Thi, Tlo, labels, assigned, p1v, p1i, p2p);
  k_assign2<<<N_TGT/4, 256, 0, stream>>>(p1v, p1i, labels, assigned);
  k_gemm_fused<2><<<NBI * NBJ, 256, 0, stream>>>(Shi, Slo, Thi, Tlo, labels, assigned, p1v, p1i, p2p);
  k_score2<<<N_TGT/4, 256, 0, stream>>>(p2p, scores, contrastA);
  k_finalize<<<1, 1024, 0, stream>>>(scores, contrastA, out);
}